// Round 8
// baseline (139.551 us; speedup 1.0000x reference)
//
#include <hip/hip_runtime.h>
#include <hip/hip_bf16.h>

// B=8, S=4096, H=8, HKV=2, D=64, HID=512. M_TOT=32768, K=512.
// Pipeline:
//   K0 convert_x   : x f32 -> xb bf16                          (ws[0..32MB))
//   K1 transpose_w : weights -> wt bf16, pre-tiled 128-col LDS panels
//                    (10 blocks of 128 cols; elem = (n>>7)*65536 + ((k>>3)*128+(n&127))*8 + (k&7))
//   K2 gemm_persist<6,0>  : xb @ wt[blk 0..5]  -> qkv bf16     (ws[32..80MB))
//   K3 attn_heads  : RoPE + analytic GQA 8x8 head-attn -> out2 (aliases xb)
//   K4 gemm_persist<4,6>  : out2 @ wt[blk 6..9] -> d_out f32
// GEMM block: 1024 thr (16 waves as 8m x 2n), 512 rows x 128 cols. B panel
// (128c x 512k = 128KB) persistent in LDS -> 1 block/CU, 16 waves/CU
// (4/SIMD). ONE barrier; K-loop barrier-free: each wave register-streams its
// 64 A-rows (1-step prefetch) against LDS B; A re-read 6x/4x -> per-XCD
// A working set 4MB = L2-resident. Bijective XCD swizzle, n-fastest.
// attn: 8 lanes per position, ushort8 loads, lane-local RoPE pairs,
// 3-hop shuffle dots, 1KB-contiguous stores.
// Scramble (ref transpose(0,2,1,3).reshape): attnout[b,t,h,d] ->
//   out2 row = h*512 + t/8, col = (t%8)*64 + d (per batch).

#define M_TOT 32768
#define K_DIM 512

typedef __bf16 bf16x8 __attribute__((ext_vector_type(8)));
typedef float f32x4 __attribute__((ext_vector_type(4)));
typedef unsigned short ushort8 __attribute__((ext_vector_type(8)));

__device__ __forceinline__ void gload_lds16(const __hip_bfloat16* g,
                                            __hip_bfloat16* l) {
  __builtin_amdgcn_global_load_lds(
      (const __attribute__((address_space(1))) unsigned int*)g,
      (__attribute__((address_space(3))) unsigned int*)l, 16, 0, 0);
}

__device__ __forceinline__ float bf2f(unsigned short u) {
  union { unsigned int i; float f; } c;
  c.i = (unsigned int)u << 16;
  return c.f;
}

__global__ __launch_bounds__(256) void convert_x(
    const float* __restrict__ x, __hip_bfloat16* __restrict__ xb) {
  size_t i = ((size_t)blockIdx.x * 256 + threadIdx.x) * 8;
  float4 a = *(const float4*)(x + i);
  float4 b = *(const float4*)(x + i + 4);
  ushort8 o;
  float va[8] = {a.x, a.y, a.z, a.w, b.x, b.y, b.z, b.w};
#pragma unroll
  for (int j = 0; j < 8; ++j) {
    __hip_bfloat16 t = __float2bfloat16(va[j]);
    o[j] = *(unsigned short*)&t;
  }
  *(ushort8*)(xb + i) = o;
}

// wt pre-tiled, 128-col panels: col n (0..1279), k (0..511):
// elem = (n>>7)*65536 + ((k>>3)*128 + (n&127))*8 + (k&7).
__global__ __launch_bounds__(256) void transpose_w(
    const float* __restrict__ wq, const float* __restrict__ wk,
    const float* __restrict__ wv, const float* __restrict__ wo,
    __hip_bfloat16* __restrict__ wt) {
  __shared__ float tile[32][33];
  int n0 = blockIdx.x * 32, k0 = blockIdx.y * 32;
  const float* W;
  int ld, nc;
  if (n0 < 512)      { W = wq; ld = 512; nc = n0; }
  else if (n0 < 640) { W = wk; ld = 128; nc = n0 - 512; }
  else if (n0 < 768) { W = wv; ld = 128; nc = n0 - 640; }
  else               { W = wo; ld = 512; nc = n0 - 768; }
  int x = threadIdx.x & 31, y = threadIdx.x >> 5;
#pragma unroll
  for (int i = 0; i < 4; ++i)
    tile[y + 8 * i][x] = W[(size_t)(k0 + y + 8 * i) * ld + nc + x];
  __syncthreads();
#pragma unroll
  for (int i = 0; i < 4; ++i) {
    int n = n0 + y + 8 * i, k = k0 + x;
    wt[((size_t)(n >> 7) << 16) + ((size_t)((k >> 3) * 128 + (n & 127))) * 8 +
       (k & 7)] = __float2bfloat16(tile[x][y + 8 * i]);
  }
}

// Persistent-B register-streaming GEMM, 128-col panels, 16-wave blocks.
// A (M_TOT x 512 bf16 row-major), wt slot-tiled, C (M_TOT x NT*128).
// Block: 512 rows x 128 cols; wave w (0..15): wr=w>>1 row-subtile, wc=w&1
// col-subtile; each wave 64 rows x 64 cols, acc[4][4].
template <int NT, int NB0, typename OutT>
__global__ __launch_bounds__(1024, 4) void gemm_persist(
    const __hip_bfloat16* __restrict__ A, const __hip_bfloat16* __restrict__ wt,
    OutT* __restrict__ C) {
  constexpr int N = NT * 128;
  __shared__ __hip_bfloat16 Bl[65536];  // 128KB: slot(kg 0..63, col 0..127) 16B
  const int tid = threadIdx.x;
  const int lane = tid & 63;
  const int w = tid >> 6;            // 0..15
  const int wr = w >> 1, wc = w & 1; // 8x2
  constexpr int NWG = (M_TOT / 512) * NT;  // 64*NT
  const int ng = (blockIdx.x & 7) * (NWG / 8) + (blockIdx.x >> 3);
  const int m0 = (ng / NT) * 512;
  const int n0 = (ng % NT) * 128;

  // Stage B panel: 8192 slots, 8 linear loads per thread, ONE barrier.
  {
    const __hip_bfloat16* Bblk = wt + ((size_t)(NB0 + ng % NT) << 16);
#pragma unroll
    for (int j = 0; j < 8; ++j)
      gload_lds16(Bblk + (size_t)(j * 1024 + tid) * 8,
                  &Bl[(j * 1024 + w * 64) * 8]);
  }
  asm volatile("s_waitcnt vmcnt(0)" ::: "memory");
  __syncthreads();  // ONLY barrier; Bl read-only hereafter.

  const int kbq = lane >> 4, fr = lane & 15;
  // A frag mi at step ks: row m0 + wr*64 + mi*16 + fr, k = ks*32 + kbq*8.
  const __hip_bfloat16* pA = A + (size_t)(m0 + wr * 64 + fr) * 512 + kbq * 8;

  f32x4 acc[4][4] = {};
  bf16x8 a[2][4];
#pragma unroll
  for (int mi = 0; mi < 4; ++mi)
    a[0][mi] = *(const bf16x8*)(pA + mi * 16 * 512);

#pragma unroll
  for (int ks = 0; ks < 16; ++ks) {
    bf16x8 b[4];
#pragma unroll
    for (int ni = 0; ni < 4; ++ni)
      b[ni] = *(const bf16x8*)
          &Bl[((ks * 4 + kbq) * 128 + wc * 64 + ni * 16 + fr) * 8];
    if (ks < 15) {
#pragma unroll
      for (int mi = 0; mi < 4; ++mi)
        a[(ks + 1) & 1][mi] =
            *(const bf16x8*)(pA + mi * 16 * 512 + (ks + 1) * 32);
    }
#pragma unroll
    for (int mi = 0; mi < 4; ++mi)
#pragma unroll
      for (int ni = 0; ni < 4; ++ni)
        acc[mi][ni] = __builtin_amdgcn_mfma_f32_16x16x32_bf16(
            a[ks & 1][mi], b[ni], acc[mi][ni], 0, 0, 0);
  }

  // C/D layout: col=lane&15, row=(lane>>4)*4+reg  [m89]
#pragma unroll
  for (int mi = 0; mi < 4; ++mi) {
#pragma unroll
    for (int ni = 0; ni < 4; ++ni) {
      int col = n0 + wc * 64 + ni * 16 + (lane & 15);
#pragma unroll
      for (int r = 0; r < 4; ++r) {
        int row = m0 + wr * 64 + mi * 16 + (lane >> 4) * 4 + r;
        if constexpr (sizeof(OutT) == 2)
          C[(size_t)row * N + col] = __float2bfloat16(acc[mi][ni][r]);
        else
          C[(size_t)row * N + col] = acc[mi][ni][r];
      }
    }
  }
}

// attn: 8 lanes per position (pos=lane>>3, dlane=lane&7), each lane owns
// d = dlane*8..+8 (16B vector). RoPE pairs are lane-local. Dots reduce over
// dlane via shfl_xor 1/2/4. Wave = 8 consecutive positions; stores are
// 1KB-contiguous per head.
__global__ __launch_bounds__(256) void attn_heads(
    const __hip_bfloat16* __restrict__ qkv, const float* __restrict__ fcos,
    const float* __restrict__ fsin, __hip_bfloat16* __restrict__ out2) {
  const int lane = threadIdx.x & 63;
  const int wvid = blockIdx.x * 4 + (threadIdx.x >> 6);  // 0..4095
  const int pos = lane >> 3, dlane = lane & 7;
  const int gt = wvid * 8 + pos;  // global position b*4096+t
  const int b = gt >> 12, t = gt & 4095;
  const size_t row = (size_t)gt * 768;

  // cos/sin for this lane's 4 pairs.
  f32x4 c4 = *(const f32x4*)&fcos[(size_t)t * 32 + dlane * 4];
  f32x4 s4 = *(const f32x4*)&fsin[(size_t)t * 32 + dlane * 4];

  float q[8][8], k[2][8], v[2][8];
#pragma unroll
  for (int h = 0; h < 8; ++h) {
    ushort8 u = *(const ushort8*)&qkv[row + h * 64 + dlane * 8];
#pragma unroll
    for (int j = 0; j < 4; ++j) {
      float xr = bf2f(u[2 * j]), xi = bf2f(u[2 * j + 1]);
      q[h][2 * j] = xr * c4[j] - xi * s4[j];
      q[h][2 * j + 1] = xr * s4[j] + xi * c4[j];
    }
  }
#pragma unroll
  for (int c = 0; c < 2; ++c) {
    ushort8 uk = *(const ushort8*)&qkv[row + 512 + c * 64 + dlane * 8];
    ushort8 uv = *(const ushort8*)&qkv[row + 640 + c * 64 + dlane * 8];
#pragma unroll
    for (int j = 0; j < 4; ++j) {
      float xr = bf2f(uk[2 * j]), xi = bf2f(uk[2 * j + 1]);
      k[c][2 * j] = xr * c4[j] - xi * s4[j];
      k[c][2 * j + 1] = xr * s4[j] + xi * c4[j];
    }
#pragma unroll
    for (int j = 0; j < 8; ++j) v[c][j] = bf2f(uv[j]);
  }

  float dot[8][2];
#pragma unroll
  for (int h = 0; h < 8; ++h)
#pragma unroll
    for (int c = 0; c < 2; ++c) {
      float p = 0.f;
#pragma unroll
      for (int j = 0; j < 8; ++j) p += q[h][j] * k[c][j];
      p += __shfl_xor(p, 1);
      p += __shfl_xor(p, 2);
      p += __shfl_xor(p, 4);
      dot[h][c] = p * 0.125f;  // 1/sqrt(64)
    }

#pragma unroll
  for (int h = 0; h < 8; ++h) {
    int c0 = (h + 1 < 4) ? (h + 1) : 4;
    int c1 = (h + 1) - c0;
    float w0, w1;
    if (c1 > 0) {
      float s0 = dot[h][0], s1 = dot[h][1];
      float m = fmaxf(s0, s1);
      float e0 = (float)c0 * expf(s0 - m), e1 = (float)c1 * expf(s1 - m);
      float inv = 1.f / (e0 + e1);
      w0 = e0 * inv;
      w1 = e1 * inv;
    } else {
      w0 = 1.f;
      w1 = 0.f;
    }
    ushort8 o;
#pragma unroll
    for (int j = 0; j < 8; ++j) {
      __hip_bfloat16 ob = __float2bfloat16(w0 * v[0][j] + w1 * v[1][j]);
      o[j] = *(unsigned short*)&ob;
    }
    *(ushort8*)&out2[((size_t)(b * 4096 + h * 512 + (t >> 3))) * 512 +
                     pos * 64 + dlane * 8] = o;
  }
}

extern "C" void kernel_launch(void* const* d_in, const int* in_sizes, int n_in,
                              void* d_out, int out_size, void* d_ws,
                              size_t ws_size, hipStream_t stream) {
  const float* x    = (const float*)d_in[0];
  const float* fcos = (const float*)d_in[1];
  const float* fsin = (const float*)d_in[2];
  const float* wq   = (const float*)d_in[3];
  const float* wk   = (const float*)d_in[4];
  const float* wv   = (const float*)d_in[5];
  const float* wo   = (const float*)d_in[6];
  float* out = (float*)d_out;

  __hip_bfloat16* xb   = (__hip_bfloat16*)d_ws;  // 32MB
  __hip_bfloat16* out2 = xb;                      // alias (xb dead after qkv gemm)
  __hip_bfloat16* qkv  = (__hip_bfloat16*)((char*)d_ws + (size_t)M_TOT * 512 * 2);  // 48MB
  __hip_bfloat16* wt   = (__hip_bfloat16*)((char*)d_ws + (size_t)M_TOT * 512 * 2 +
                                           (size_t)M_TOT * 768 * 2);  // 1.31MB

  convert_x<<<dim3(M_TOT * 512 / 8 / 256), 256, 0, stream>>>(x, xb);
  transpose_w<<<dim3(1280 / 32, 512 / 32), 256, 0, stream>>>(wq, wk, wv, wo, wt);
  gemm_persist<6, 0, __hip_bfloat16><<<dim3(384), 1024, 0, stream>>>(xb, wt, qkv);
  attn_heads<<<dim3(M_TOT / 8 / 4), 256, 0, stream>>>(qkv, fcos, fsin, out2);
  gemm_persist<4, 6, float><<<dim3(256), 1024, 0, stream>>>(out2, wt, out);
}

// Round 9
// 98.000 us; speedup vs baseline: 1.4240x; 1.4240x over previous
//
#include <hip/hip_runtime.h>
#include <hip/hip_bf16.h>

// B=8, S=4096, H=8, HKV=2, D=64, HID=512. M_TOT=32768, K=512.
// Pipeline:
//   K0 convert_x   : x f32 -> xb bf16                          (ws[0..32MB))
//   K1 transpose_w : weights -> wt bf16, pre-tiled 128-col LDS panels
//   K2 gemm_persist<6,0,2>  : xb @ wt[blk 0..5]  -> qkv bf16   (ws[32..80MB))
//   K3 attn_heads  : RoPE + analytic GQA 8x8 head-attn -> out2 (aliases xb)
//   K4 gemm_persist<4,6,4>  : out2 @ wt[blk 6..9] -> d_out f32
// GEMM: persistent 128-col B panel (128KB LDS, staged once, ONE barrier),
// 512 thr / 8 waves. Wave owns (MI*16) rows x 128 cols, acc[MI][8].
// K-loop barrier-free, register double-buffered: next step's A globals and
// B ds_reads issue BEFORE current step's MFMAs (lgkm wait hides under MFMA).
// gemm6: MI=2 -> 768 blocks = 3 exact rounds (balanced).
// gemm4: MI=4 -> 256 blocks = 1 exact round.
// Bijective XCD swizzle, n-fastest (per-XCD A working set 4MB = L2).
// Scramble (ref transpose(0,2,1,3).reshape): attnout[b,t,h,d] ->
//   out2 row = h*512 + t/8, col = (t%8)*64 + d (per batch).

#define M_TOT 32768
#define K_DIM 512

typedef __bf16 bf16x8 __attribute__((ext_vector_type(8)));
typedef float f32x4 __attribute__((ext_vector_type(4)));
typedef unsigned short ushort8 __attribute__((ext_vector_type(8)));

__device__ __forceinline__ void gload_lds16(const __hip_bfloat16* g,
                                            __hip_bfloat16* l) {
  __builtin_amdgcn_global_load_lds(
      (const __attribute__((address_space(1))) unsigned int*)g,
      (__attribute__((address_space(3))) unsigned int*)l, 16, 0, 0);
}

__device__ __forceinline__ float bf2f(unsigned short u) {
  union { unsigned int i; float f; } c;
  c.i = (unsigned int)u << 16;
  return c.f;
}

__global__ __launch_bounds__(256) void convert_x(
    const float* __restrict__ x, __hip_bfloat16* __restrict__ xb) {
  size_t i = ((size_t)blockIdx.x * 256 + threadIdx.x) * 8;
  float4 a = *(const float4*)(x + i);
  float4 b = *(const float4*)(x + i + 4);
  ushort8 o;
  float va[8] = {a.x, a.y, a.z, a.w, b.x, b.y, b.z, b.w};
#pragma unroll
  for (int j = 0; j < 8; ++j) {
    __hip_bfloat16 t = __float2bfloat16(va[j]);
    o[j] = *(unsigned short*)&t;
  }
  *(ushort8*)(xb + i) = o;
}

// wt pre-tiled, 128-col panels: col n (0..1279), k (0..511):
// elem = (n>>7)*65536 + ((k>>3)*128 + (n&127))*8 + (k&7).
__global__ __launch_bounds__(256) void transpose_w(
    const float* __restrict__ wq, const float* __restrict__ wk,
    const float* __restrict__ wv, const float* __restrict__ wo,
    __hip_bfloat16* __restrict__ wt) {
  __shared__ float tile[32][33];
  int n0 = blockIdx.x * 32, k0 = blockIdx.y * 32;
  const float* W;
  int ld, nc;
  if (n0 < 512)      { W = wq; ld = 512; nc = n0; }
  else if (n0 < 640) { W = wk; ld = 128; nc = n0 - 512; }
  else if (n0 < 768) { W = wv; ld = 128; nc = n0 - 640; }
  else               { W = wo; ld = 512; nc = n0 - 768; }
  int x = threadIdx.x & 31, y = threadIdx.x >> 5;
#pragma unroll
  for (int i = 0; i < 4; ++i)
    tile[y + 8 * i][x] = W[(size_t)(k0 + y + 8 * i) * ld + nc + x];
  __syncthreads();
#pragma unroll
  for (int i = 0; i < 4; ++i) {
    int n = n0 + y + 8 * i, k = k0 + x;
    wt[((size_t)(n >> 7) << 16) + ((size_t)((k >> 3) * 128 + (n & 127))) * 8 +
       (k & 7)] = __float2bfloat16(tile[x][y + 8 * i]);
  }
}

// Persistent-B register-streaming GEMM, 128-col panels, 8-wave blocks.
// Block: (MI*128) rows x 128 cols; wave w owns rows [w*MI*16, +MI*16).
// Register-dbuf K-loop: prefetch a/b for step ks+1 before MFMAs of step ks.
template <int NT, int NB0, int MI, typename OutT>
__global__ __launch_bounds__(512, 2) void gemm_persist(
    const __hip_bfloat16* __restrict__ A, const __hip_bfloat16* __restrict__ wt,
    OutT* __restrict__ C) {
  constexpr int N = NT * 128;
  constexpr int MT = MI * 128;  // rows per block
  __shared__ __hip_bfloat16 Bl[65536];  // 128KB: slot(kg 0..63, col 0..127) 16B
  const int tid = threadIdx.x;
  const int lane = tid & 63;
  const int w = tid >> 6;  // 0..7
  constexpr int NWG = (M_TOT / MT) * NT;
  const int ng = (blockIdx.x & 7) * (NWG / 8) + (blockIdx.x >> 3);
  const int m0 = (ng / NT) * MT;
  const int n0 = (ng % NT) * 128;

  // Stage B panel: 8192 slots, 16 linear wave-loads per thread, ONE barrier.
  {
    const __hip_bfloat16* Bblk = wt + ((size_t)(NB0 + ng % NT) << 16);
#pragma unroll
    for (int j = 0; j < 16; ++j)
      gload_lds16(Bblk + (size_t)(j * 512 + w * 64 + lane) * 8,
                  &Bl[(j * 512 + w * 64) * 8]);
  }
  asm volatile("s_waitcnt vmcnt(0)" ::: "memory");
  __syncthreads();  // ONLY barrier; Bl read-only hereafter.

  const int kbq = lane >> 4, fr = lane & 15;
  // A frag mi at step ks: row m0 + w*MI*16 + mi*16 + fr, k = ks*32 + kbq*8.
  const __hip_bfloat16* pA =
      A + (size_t)(m0 + w * MI * 16 + fr) * 512 + kbq * 8;

  f32x4 acc[MI][8] = {};
  bf16x8 a[2][MI], b[2][8];
#pragma unroll
  for (int mi = 0; mi < MI; ++mi)
    a[0][mi] = *(const bf16x8*)(pA + mi * 16 * 512);
#pragma unroll
  for (int ni = 0; ni < 8; ++ni)
    b[0][ni] = *(const bf16x8*)&Bl[(kbq * 128 + ni * 16 + fr) * 8];

#pragma unroll
  for (int ks = 0; ks < 16; ++ks) {
    const int cur = ks & 1;
    if (ks < 15) {
      // issue next step's loads first; MFMAs below hide their latency
#pragma unroll
      for (int mi = 0; mi < MI; ++mi)
        a[cur ^ 1][mi] =
            *(const bf16x8*)(pA + mi * 16 * 512 + (ks + 1) * 32);
#pragma unroll
      for (int ni = 0; ni < 8; ++ni)
        b[cur ^ 1][ni] = *(const bf16x8*)
            &Bl[(((ks + 1) * 4 + kbq) * 128 + ni * 16 + fr) * 8];
    }
#pragma unroll
    for (int mi = 0; mi < MI; ++mi)
#pragma unroll
      for (int ni = 0; ni < 8; ++ni)
        acc[mi][ni] = __builtin_amdgcn_mfma_f32_16x16x32_bf16(
            a[cur][mi], b[cur][ni], acc[mi][ni], 0, 0, 0);
  }

  // C/D layout: col=lane&15, row=(lane>>4)*4+reg  [m89]
#pragma unroll
  for (int mi = 0; mi < MI; ++mi) {
#pragma unroll
    for (int ni = 0; ni < 8; ++ni) {
      int col = n0 + ni * 16 + (lane & 15);
#pragma unroll
      for (int r = 0; r < 4; ++r) {
        int row = m0 + w * MI * 16 + mi * 16 + (lane >> 4) * 4 + r;
        if constexpr (sizeof(OutT) == 2)
          C[(size_t)row * N + col] = __float2bfloat16(acc[mi][ni][r]);
        else
          C[(size_t)row * N + col] = acc[mi][ni][r];
      }
    }
  }
}

// attn: 8 lanes per position (pos=lane>>3, dlane=lane&7), each lane owns
// d = dlane*8..+8 (16B vector). RoPE pairs lane-local. Dots reduce over
// dlane via shfl_xor 1/2/4. Wave = 8 consecutive positions; stores are
// 1KB-contiguous per head.
__global__ __launch_bounds__(256) void attn_heads(
    const __hip_bfloat16* __restrict__ qkv, const float* __restrict__ fcos,
    const float* __restrict__ fsin, __hip_bfloat16* __restrict__ out2) {
  const int lane = threadIdx.x & 63;
  const int wvid = blockIdx.x * 4 + (threadIdx.x >> 6);  // 0..4095
  const int pos = lane >> 3, dlane = lane & 7;
  const int gt = wvid * 8 + pos;  // global position b*4096+t
  const int b = gt >> 12, t = gt & 4095;
  const size_t row = (size_t)gt * 768;

  f32x4 c4 = *(const f32x4*)&fcos[(size_t)t * 32 + dlane * 4];
  f32x4 s4 = *(const f32x4*)&fsin[(size_t)t * 32 + dlane * 4];

  float q[8][8], k[2][8], v[2][8];
#pragma unroll
  for (int h = 0; h < 8; ++h) {
    ushort8 u = *(const ushort8*)&qkv[row + h * 64 + dlane * 8];
#pragma unroll
    for (int j = 0; j < 4; ++j) {
      float xr = bf2f(u[2 * j]), xi = bf2f(u[2 * j + 1]);
      q[h][2 * j] = xr * c4[j] - xi * s4[j];
      q[h][2 * j + 1] = xr * s4[j] + xi * c4[j];
    }
  }
#pragma unroll
  for (int c = 0; c < 2; ++c) {
    ushort8 uk = *(const ushort8*)&qkv[row + 512 + c * 64 + dlane * 8];
    ushort8 uv = *(const ushort8*)&qkv[row + 640 + c * 64 + dlane * 8];
#pragma unroll
    for (int j = 0; j < 4; ++j) {
      float xr = bf2f(uk[2 * j]), xi = bf2f(uk[2 * j + 1]);
      k[c][2 * j] = xr * c4[j] - xi * s4[j];
      k[c][2 * j + 1] = xr * s4[j] + xi * c4[j];
    }
#pragma unroll
    for (int j = 0; j < 8; ++j) v[c][j] = bf2f(uv[j]);
  }

  float dot[8][2];
#pragma unroll
  for (int h = 0; h < 8; ++h)
#pragma unroll
    for (int c = 0; c < 2; ++c) {
      float p = 0.f;
#pragma unroll
      for (int j = 0; j < 8; ++j) p += q[h][j] * k[c][j];
      p += __shfl_xor(p, 1);
      p += __shfl_xor(p, 2);
      p += __shfl_xor(p, 4);
      dot[h][c] = p * 0.125f;  // 1/sqrt(64)
    }

#pragma unroll
  for (int h = 0; h < 8; ++h) {
    int c0 = (h + 1 < 4) ? (h + 1) : 4;
    int c1 = (h + 1) - c0;
    float w0, w1;
    if (c1 > 0) {
      float s0 = dot[h][0], s1 = dot[h][1];
      float m = fmaxf(s0, s1);
      float e0 = (float)c0 * expf(s0 - m), e1 = (float)c1 * expf(s1 - m);
      float inv = 1.f / (e0 + e1);
      w0 = e0 * inv;
      w1 = e1 * inv;
    } else {
      w0 = 1.f;
      w1 = 0.f;
    }
    ushort8 o;
#pragma unroll
    for (int j = 0; j < 8; ++j) {
      __hip_bfloat16 ob = __float2bfloat16(w0 * v[0][j] + w1 * v[1][j]);
      o[j] = *(unsigned short*)&ob;
    }
    *(ushort8*)&out2[((size_t)(b * 4096 + h * 512 + (t >> 3))) * 512 +
                     pos * 64 + dlane * 8] = o;
  }
}

extern "C" void kernel_launch(void* const* d_in, const int* in_sizes, int n_in,
                              void* d_out, int out_size, void* d_ws,
                              size_t ws_size, hipStream_t stream) {
  const float* x    = (const float*)d_in[0];
  const float* fcos = (const float*)d_in[1];
  const float* fsin = (const float*)d_in[2];
  const float* wq   = (const float*)d_in[3];
  const float* wk   = (const float*)d_in[4];
  const float* wv   = (const float*)d_in[5];
  const float* wo   = (const float*)d_in[6];
  float* out = (float*)d_out;

  __hip_bfloat16* xb   = (__hip_bfloat16*)d_ws;  // 32MB
  __hip_bfloat16* out2 = xb;                      // alias (xb dead after qkv gemm)
  __hip_bfloat16* qkv  = (__hip_bfloat16*)((char*)d_ws + (size_t)M_TOT * 512 * 2);  // 48MB
  __hip_bfloat16* wt   = (__hip_bfloat16*)((char*)d_ws + (size_t)M_TOT * 512 * 2 +
                                           (size_t)M_TOT * 768 * 2);  // 1.31MB

  convert_x<<<dim3(M_TOT * 512 / 8 / 256), 256, 0, stream>>>(x, xb);
  transpose_w<<<dim3(1280 / 32, 512 / 32), 256, 0, stream>>>(wq, wk, wv, wo, wt);
  gemm_persist<6, 0, 2, __hip_bfloat16><<<dim3(768), 512, 0, stream>>>(xb, wt, qkv);
  attn_heads<<<dim3(M_TOT / 8 / 4), 256, 0, stream>>>(qkv, fcos, fsin, out2);
  gemm_persist<4, 6, 4, float><<<dim3(256), 512, 0, stream>>>(out2, wt, out);
}